// Round 4
// baseline (268.297 us; speedup 1.0000x reference)
//
#include <hip/hip_runtime.h>
#include <cstdint>
#include <cstddef>

#define B_    8
#define N_    2048
#define FIN   128
#define FOUT  64
#define ALPHA 0.2f
#define LOG2E 1.4426950408889634f

typedef __attribute__((ext_vector_type(8))) _Float16 half8;
typedef __attribute__((ext_vector_type(4))) _Float16 half4;
typedef __attribute__((ext_vector_type(4))) float float4v;

// ---------------------------------------------------------------------------
// Kernel 0: W [128][64] fp32 -> WtG fp16, transposed [f][k], split hi/lo
// planes (error-compensated fp16: v = hi + lo exactly to fp32 precision).
// ---------------------------------------------------------------------------
__global__ __launch_bounds__(256) void k0_convW(
    const float* __restrict__ W, _Float16* __restrict__ WtG)
{
    int o = blockIdx.x * 256 + threadIdx.x;   // 0..8191, grid 32x256
    int f = o >> 7, k = o & 127;
    float v = W[k * FOUT + f];
    _Float16 hi = (_Float16)v;
    _Float16 lo = (_Float16)(v - (float)hi);
    WtG[o] = hi;                              // plane 0: hi
    WtG[FOUT * FIN + o] = lo;                 // plane 1: lo
}

// ---------------------------------------------------------------------------
// Kernel P: adj int32 (134 MB) -> bitmask (4 MB). Pure HBM stream, zero
// dependencies: lane reads adj[row][it*64+lane] (256 B/wave coalesced),
// ballot packs 64 cols into one uint64. Word w of row = cols [w*64,w*64+64),
// bit c = adj[col w*64+c] > 0. 32 independent loads/wave -> deep pipeline.
// ---------------------------------------------------------------------------
__global__ __launch_bounds__(256) void kp_pack(
    const int* __restrict__ adj, unsigned long long* __restrict__ maskp)
{
    int t = threadIdx.x, lane = t & 63, w = t >> 6;
    size_t row = (size_t)blockIdx.x * 4 + w;          // grid 4096, 1 row/wave
    const int* rp = adj + row * N_ + lane;
    unsigned long long* orow = maskp + row * 32;
    #pragma unroll
    for (int it = 0; it < 32; ++it) {
        int a = rp[it * 64];
        unsigned long long m = __ballot(a > 0);
        if (lane == 0) orow[it] = m;
    }
}

// ---------------------------------------------------------------------------
// Kernel 1: wh = x @ W via MFMA 16x16x32 f16 with split-fp16 compensation
// (acc = ah*bh + ah*bl + al*bh -> fp32-level accuracy). Unchanged.
// ---------------------------------------------------------------------------
__global__ __launch_bounds__(256, 2) void k1_wh(
    const float* __restrict__ x, const _Float16* __restrict__ WtG,
    const float* __restrict__ w2, _Float16* __restrict__ whT,
    float* __restrict__ s1, float* __restrict__ s2)
{
    __shared__ __attribute__((aligned(16))) _Float16 xth[32][136];
    __shared__ __attribute__((aligned(16))) _Float16 xtl[32][136];
    __shared__ float s1p[4][32];
    __shared__ float s2p[4][32];

    int t = threadIdx.x, lane = t & 63, w = t >> 6;
    int b = blockIdx.x >> 6;
    int r0 = (blockIdx.x & 63) << 5;          // 32 rows per block
    const float* xb = x + ((size_t)b * N_ + r0) * FIN;

    #pragma unroll
    for (int j = 0; j < 4; ++j) {
        int idx = t + j * 256;
        int row = idx >> 5;
        int k0 = (idx & 31) * 4;
        float4 v = ((const float4*)xb)[idx];
        float vv[4] = {v.x, v.y, v.z, v.w};
        half4 h, l;
        #pragma unroll
        for (int e = 0; e < 4; ++e) {
            _Float16 hi = (_Float16)vv[e];
            h[e] = hi;
            l[e] = (_Float16)(vv[e] - (float)hi);
        }
        *(half4*)&xth[row][k0] = h;
        *(half4*)&xtl[row][k0] = l;
    }
    __syncthreads();

    int l15 = lane & 15, quad = lane >> 4;
    int f0 = w * 16;

    half8 bh[4], bl[4];
    const _Float16* wgh = WtG + (f0 + l15) * FIN + quad * 8;
    #pragma unroll
    for (int c = 0; c < 4; ++c) {
        bh[c] = *(const half8*)(wgh + c * 32);
        bl[c] = *(const half8*)(wgh + FOUT * FIN + c * 32);
    }
    float a1f = w2[f0 + l15], a2f = w2[FOUT + f0 + l15];

    #pragma unroll
    for (int rt = 0; rt < 2; ++rt) {
        float4v acc = {0.f, 0.f, 0.f, 0.f};
        #pragma unroll
        for (int c = 0; c < 4; ++c) {
            half8 ah = *(const half8*)&xth[rt * 16 + l15][c * 32 + quad * 8];
            half8 al = *(const half8*)&xtl[rt * 16 + l15][c * 32 + quad * 8];
            acc = __builtin_amdgcn_mfma_f32_16x16x32_f16(ah, bh[c], acc, 0, 0, 0);
            acc = __builtin_amdgcn_mfma_f32_16x16x32_f16(ah, bl[c], acc, 0, 0, 0);
            acc = __builtin_amdgcn_mfma_f32_16x16x32_f16(al, bh[c], acc, 0, 0, 0);
        }
        half4 hv;
        #pragma unroll
        for (int reg = 0; reg < 4; ++reg) hv[reg] = (_Float16)acc[reg];
        *(half4*)(whT + ((size_t)b * FOUT + f0 + l15) * N_ + r0 + rt * 16 + quad * 4) = hv;

        #pragma unroll
        for (int reg = 0; reg < 4; ++reg) {
            float v1 = acc[reg] * a1f;
            float v2 = acc[reg] * a2f;
            #pragma unroll
            for (int m = 1; m <= 8; m <<= 1) {
                v1 += __shfl_xor(v1, m);
                v2 += __shfl_xor(v2, m);
            }
            if (l15 == 0) {
                s1p[w][rt * 16 + quad * 4 + reg] = v1;
                s2p[w][rt * 16 + quad * 4 + reg] = v2;
            }
        }
    }
    __syncthreads();
    if (t < 32) {
        float v = s1p[0][t] + s1p[1][t] + s1p[2][t] + s1p[3][t];
        s1[(size_t)b * N_ + r0 + t] = v;
    } else if (t < 64) {
        int r = t - 32;
        float v = s2p[0][r] + s2p[1][r] + s2p[2][r] + s2p[3][r];
        s2[(size_t)b * N_ + r0 + r] = v;
    }
}

// ---------------------------------------------------------------------------
// Kernel 2: flash-style masked softmax + PV. adj replaced by the 4 MB
// bitmask (L2-resident) -> k2 has ~zero HBM traffic; all loads are small
// L2 hits hidden by 16 waves/CU. No DMA/vmcnt machinery.
// Per iter (chunk 256, 8 iters): mask words (broadcast within 16-lane
// groups, 1 line/wave) + s2 float4 + bf 8xhalf8 -> p-compute -> pT[c&1]
// -> ONE barrier -> MFMA. pT stride 264: A-read bank group 4*(l15+quad)
// mod 32 = structural-min, conflict-free.
// ---------------------------------------------------------------------------
__global__ __launch_bounds__(256, 4) void k2_attn(
    const unsigned long long* __restrict__ maskp, const _Float16* __restrict__ whT,
    const float* __restrict__ s1, const float* __restrict__ s2,
    float* __restrict__ out)
{
    __shared__ __attribute__((aligned(16))) _Float16 pT[2][16][264];    // 16.5 KB
    __shared__ float lL[16];
    __shared__ float smaxL[4];

    int t = threadIdx.x, lane = t & 63, w = t >> 6;
    int b = blockIdx.x >> 7;
    int i0 = (blockIdx.x & 127) << 4;

    // --- exact S2MAX over batch b (8 KB, L2-hot) ---
    const float4* s2v = (const float4*)(s2 + (size_t)b * N_);
    float4 ua_ = s2v[t], ub_ = s2v[t + 256];
    float vm = fmaxf(fmaxf(fmaxf(ua_.x, ua_.y), fmaxf(ua_.z, ua_.w)),
                     fmaxf(fmaxf(ub_.x, ub_.y), fmaxf(ub_.z, ub_.w)));
    #pragma unroll
    for (int m = 32; m >= 1; m >>= 1) vm = fmaxf(vm, __shfl_xor(vm, m));
    if (lane == 0) smaxL[w] = vm;
    __syncthreads();
    float s2max = fmaxf(fmaxf(smaxL[0], smaxL[1]), fmaxf(smaxL[2], smaxL[3]));

    int l15 = lane & 15, quad = lane >> 4;
    int f0 = w * 16;
    int sh4 = l15 * 4;

    // per-row folded constants (wave w owns rows w*4..w*4+3)
    float c1[4], c2[4], lacc[4];
    #pragma unroll
    for (int rr = 0; rr < 4; ++rr) {
        float sv = s1[(size_t)b * N_ + i0 + w * 4 + rr];   // wave-uniform
        float mm = sv + s2max;
        float mh = fmaxf(mm, ALPHA * mm);    // leaky(s1_i + s2max) >= row max
        c1[rr] = (sv - mh) * LOG2E;
        c2[rr] = (ALPHA * sv - mh) * LOG2E;
        lacc[rr] = 0.f;
    }

    // mask base: row (i0 + w*4), word (lane>>4); row stride 32 words
    const unsigned long long* mB =
        maskp + ((size_t)b * N_ + i0 + w * 4) * 32 + (lane >> 4);
    const float* s2L = s2 + (size_t)b * N_ + lane * 4;

    float4v acc = {0.f, 0.f, 0.f, 0.f};
    const _Float16* wB = whT + ((size_t)b * FOUT + f0 + l15) * N_ + quad * 8;

    #pragma unroll
    for (int c = 0; c < 8; ++c) {
        // chunk-c loads: mask words (8B, broadcast in 16-lane groups),
        // s2 float4, bf 8xhalf8 -- all L2-resident
        unsigned mbits[4];
        #pragma unroll
        for (int rr = 0; rr < 4; ++rr) {
            unsigned long long mw = mB[(size_t)rr * 32 + c * 4];
            mbits[rr] = (unsigned)(mw >> sh4) & 0xFu;    // 4 bits: cols lane*4..+3
        }
        float4 sv = *(const float4*)(s2L + c * 256);
        half8 bfr[8];
        const _Float16* wp = wB + c * 256;
        #pragma unroll
        for (int kk = 0; kk < 8; ++kk) bfr[kk] = *(const half8*)(wp + kk * 32);

        float u[4]  = {sv.x * LOG2E, sv.y * LOG2E, sv.z * LOG2E, sv.w * LOG2E};
        float ua[4] = {u[0] * ALPHA, u[1] * ALPHA, u[2] * ALPHA, u[3] * ALPHA};
        #pragma unroll
        for (int rr = 0; rr < 4; ++rr) {
            int r = w * 4 + rr;
            half4 pf;
            float ls = 0.f;
            #pragma unroll
            for (int e = 0; e < 4; ++e) {
                float tt = fmaxf(c1[rr] + u[e], c2[rr] + ua[e]);
#if __has_builtin(__builtin_amdgcn_exp2f)
                float p = __builtin_amdgcn_exp2f(tt);
#else
                float p = exp2f(tt);
#endif
                p = (mbits[rr] & (1u << e)) ? p : 0.f;   // mask -> exact 0
                ls += p;
                pf[e] = (_Float16)p;
            }
            lacc[rr] += ls;
            *(half4*)&pT[c & 1][r][lane * 4] = pf;
        }

        if (c == 7) {
            // publish row sums before the last barrier
            #pragma unroll
            for (int rr = 0; rr < 4; ++rr) {
                float v = lacc[rr];
                #pragma unroll
                for (int m = 32; m >= 1; m >>= 1) v += __shfl_xor(v, m);
                if (lane == 0) lL[w * 4 + rr] = v;
            }
        }

        __syncthreads();   // publish pT[c&1]; prior-buffer readers proven done

        // MFMA on pT[c&1] with reg-resident B
        #pragma unroll
        for (int kk = 0; kk < 8; ++kk) {
            half8 af = *(const half8*)&pT[c & 1][l15][kk * 32 + quad * 8];
            acc = __builtin_amdgcn_mfma_f32_16x16x32_f16(af, bfr[kk], acc, 0, 0, 0);
        }
    }

    // epilogue: normalize, ELU, store. D: row=quad*4+reg, col=f0+l15
    #pragma unroll
    for (int reg = 0; reg < 4; ++reg) {
        int row = quad * 4 + reg;
        float val = acc[reg] / lL[row];
        val = (val > 0.f) ? val : (__expf(val) - 1.f);   // ELU
        out[((size_t)b * N_ + i0 + row) * FOUT + f0 + l15] = val;
    }
}

// ---------------------------------------------------------------------------
extern "C" void kernel_launch(void* const* d_in, const int* in_sizes, int n_in,
                              void* d_out, int out_size, void* d_ws, size_t ws_size,
                              hipStream_t stream) {
    const float* x   = (const float*)d_in[0];
    const int*   adj = (const int*)d_in[1];
    const float* W   = (const float*)d_in[2];
    const float* w2  = (const float*)d_in[3];
    float* out = (float*)d_out;

    char* ws = (char*)d_ws;
    _Float16* whT = (_Float16*)ws;                              // 2 MiB
    float* s1  = (float*)(ws + 2097152);                        // 64 KiB
    float* s2  = (float*)(ws + 2097152 + 65536);                // 64 KiB
    _Float16* WtG = (_Float16*)(ws + 2097152 + 131072);         // 32 KiB
    unsigned long long* maskp =
        (unsigned long long*)(ws + 2097152 + 131072 + 32768);   // 4 MiB

    k0_convW<<<32, 256, 0, stream>>>(W, WtG);
    kp_pack<<<(B_ * N_) / 4, 256, 0, stream>>>(adj, maskp);
    k1_wh<<<(B_ * N_) / 32, 256, 0, stream>>>(x, WtG, w2, whT, s1, s2);
    k2_attn<<<(B_ * N_) / 16, 256, 0, stream>>>(maskp, whT, s1, s2, out);
}

// Round 5
// 239.852 us; speedup vs baseline: 1.1186x; 1.1186x over previous
//
#include <hip/hip_runtime.h>
#include <cstdint>
#include <cstddef>

#define B_    8
#define N_    2048
#define FIN   128
#define FOUT  64
#define ALPHA 0.2f
#define LOG2E 1.4426950408889634f

typedef __attribute__((ext_vector_type(8))) _Float16 half8;
typedef __attribute__((ext_vector_type(4))) _Float16 half4;
typedef __attribute__((ext_vector_type(4))) float float4v;

// ---------------------------------------------------------------------------
// Kernel 0: W [128][64] fp32 -> WtG fp16, transposed [f][k], split hi/lo
// planes (error-compensated fp16: v = hi + lo exactly to fp32 precision).
// ---------------------------------------------------------------------------
__global__ __launch_bounds__(256) void k0_convW(
    const float* __restrict__ W, _Float16* __restrict__ WtG)
{
    int o = blockIdx.x * 256 + threadIdx.x;   // 0..8191, grid 32x256
    int f = o >> 7, k = o & 127;
    float v = W[k * FOUT + f];
    _Float16 hi = (_Float16)v;
    _Float16 lo = (_Float16)(v - (float)hi);
    WtG[o] = hi;                              // plane 0: hi
    WtG[FOUT * FIN + o] = lo;                 // plane 1: lo
}

// ---------------------------------------------------------------------------
// Kernel P: adj int32 (134 MB) -> bitmask (4 MB). Pure HBM stream.
// One row per wave; ALL 32 row-loads issued first (independent -> single
// HBM-latency exposure), then 32 ballots. Word it of row = cols
// [it*64, it*64+64), bit c = adj[it*64+c] > 0 (ballot bit = lane = col).
// ---------------------------------------------------------------------------
__global__ __launch_bounds__(256) void kp_pack(
    const int* __restrict__ adj, unsigned long long* __restrict__ maskp)
{
    int t = threadIdx.x, lane = t & 63, w = t >> 6;
    size_t row = (size_t)blockIdx.x * 4 + w;          // grid 4096, 1 row/wave
    const int* rp = adj + row * N_ + lane;
    unsigned long long* orow = maskp + row * 32;

    int a[32];
    #pragma unroll
    for (int it = 0; it < 32; ++it) a[it] = rp[it * 64];   // 32 loads in flight
    #pragma unroll
    for (int it = 0; it < 32; ++it) {
        unsigned long long m = __ballot(a[it] > 0);
        if (lane == 0) orow[it] = m;
    }
}

// ---------------------------------------------------------------------------
// Kernel 1: wh = x @ W via MFMA 16x16x32 f16 with split-fp16 compensation
// (acc = ah*bh + ah*bl + al*bh -> fp32-level accuracy). Unchanged.
// ---------------------------------------------------------------------------
__global__ __launch_bounds__(256, 2) void k1_wh(
    const float* __restrict__ x, const _Float16* __restrict__ WtG,
    const float* __restrict__ w2, _Float16* __restrict__ whT,
    float* __restrict__ s1, float* __restrict__ s2)
{
    __shared__ __attribute__((aligned(16))) _Float16 xth[32][136];
    __shared__ __attribute__((aligned(16))) _Float16 xtl[32][136];
    __shared__ float s1p[4][32];
    __shared__ float s2p[4][32];

    int t = threadIdx.x, lane = t & 63, w = t >> 6;
    int b = blockIdx.x >> 6;
    int r0 = (blockIdx.x & 63) << 5;          // 32 rows per block
    const float* xb = x + ((size_t)b * N_ + r0) * FIN;

    #pragma unroll
    for (int j = 0; j < 4; ++j) {
        int idx = t + j * 256;
        int row = idx >> 5;
        int k0 = (idx & 31) * 4;
        float4 v = ((const float4*)xb)[idx];
        float vv[4] = {v.x, v.y, v.z, v.w};
        half4 h, l;
        #pragma unroll
        for (int e = 0; e < 4; ++e) {
            _Float16 hi = (_Float16)vv[e];
            h[e] = hi;
            l[e] = (_Float16)(vv[e] - (float)hi);
        }
        *(half4*)&xth[row][k0] = h;
        *(half4*)&xtl[row][k0] = l;
    }
    __syncthreads();

    int l15 = lane & 15, quad = lane >> 4;
    int f0 = w * 16;

    half8 bh[4], bl[4];
    const _Float16* wgh = WtG + (f0 + l15) * FIN + quad * 8;
    #pragma unroll
    for (int c = 0; c < 4; ++c) {
        bh[c] = *(const half8*)(wgh + c * 32);
        bl[c] = *(const half8*)(wgh + FOUT * FIN + c * 32);
    }
    float a1f = w2[f0 + l15], a2f = w2[FOUT + f0 + l15];

    #pragma unroll
    for (int rt = 0; rt < 2; ++rt) {
        float4v acc = {0.f, 0.f, 0.f, 0.f};
        #pragma unroll
        for (int c = 0; c < 4; ++c) {
            half8 ah = *(const half8*)&xth[rt * 16 + l15][c * 32 + quad * 8];
            half8 al = *(const half8*)&xtl[rt * 16 + l15][c * 32 + quad * 8];
            acc = __builtin_amdgcn_mfma_f32_16x16x32_f16(ah, bh[c], acc, 0, 0, 0);
            acc = __builtin_amdgcn_mfma_f32_16x16x32_f16(ah, bl[c], acc, 0, 0, 0);
            acc = __builtin_amdgcn_mfma_f32_16x16x32_f16(al, bh[c], acc, 0, 0, 0);
        }
        half4 hv;
        #pragma unroll
        for (int reg = 0; reg < 4; ++reg) hv[reg] = (_Float16)acc[reg];
        *(half4*)(whT + ((size_t)b * FOUT + f0 + l15) * N_ + r0 + rt * 16 + quad * 4) = hv;

        #pragma unroll
        for (int reg = 0; reg < 4; ++reg) {
            float v1 = acc[reg] * a1f;
            float v2 = acc[reg] * a2f;
            #pragma unroll
            for (int m = 1; m <= 8; m <<= 1) {
                v1 += __shfl_xor(v1, m);
                v2 += __shfl_xor(v2, m);
            }
            if (l15 == 0) {
                s1p[w][rt * 16 + quad * 4 + reg] = v1;
                s2p[w][rt * 16 + quad * 4 + reg] = v2;
            }
        }
    }
    __syncthreads();
    if (t < 32) {
        float v = s1p[0][t] + s1p[1][t] + s1p[2][t] + s1p[3][t];
        s1[(size_t)b * N_ + r0 + t] = v;
    } else if (t < 64) {
        int r = t - 32;
        float v = s2p[0][r] + s2p[1][r] + s2p[2][r] + s2p[3][r];
        s2[(size_t)b * N_ + r0 + r] = v;
    }
}

// ---------------------------------------------------------------------------
// Kernel 2: flash-style masked softmax + PV on the 4 MB bitmask (L2-hot,
// ~zero HBM). Chunk loop is ROLLED (#pragma unroll 1): bounds the live set
// to one chunk's loads (~75 VGPR, no spill) -- the R4 full unroll let LLVM
// hoist 64 half8 loads across barriers and spill to scratch.
// Mask read as uint32 (same bytes as kp's uint64, little-endian): word
// c*8+(lane>>3), bits (lane&7)*4+e -- 4B broadcast load + 1 shift + and.
// pT stride 264: A-read bank group 4*(l15+quad) mod 32, conflict-free.
// ---------------------------------------------------------------------------
__global__ __launch_bounds__(256, 4) void k2_attn(
    const unsigned* __restrict__ mask32, const _Float16* __restrict__ whT,
    const float* __restrict__ s1, const float* __restrict__ s2,
    float* __restrict__ out)
{
    __shared__ __attribute__((aligned(16))) _Float16 pT[2][16][264];    // 16.5 KB
    __shared__ float lL[16];
    __shared__ float smaxL[4];

    int t = threadIdx.x, lane = t & 63, w = t >> 6;
    int b = blockIdx.x >> 7;
    int i0 = (blockIdx.x & 127) << 4;

    // --- exact S2MAX over batch b (8 KB, L2-hot) ---
    const float4* s2v = (const float4*)(s2 + (size_t)b * N_);
    float4 ua_ = s2v[t], ub_ = s2v[t + 256];
    float vm = fmaxf(fmaxf(fmaxf(ua_.x, ua_.y), fmaxf(ua_.z, ua_.w)),
                     fmaxf(fmaxf(ub_.x, ub_.y), fmaxf(ub_.z, ub_.w)));
    #pragma unroll
    for (int m = 32; m >= 1; m >>= 1) vm = fmaxf(vm, __shfl_xor(vm, m));
    if (lane == 0) smaxL[w] = vm;
    __syncthreads();
    float s2max = fmaxf(fmaxf(smaxL[0], smaxL[1]), fmaxf(smaxL[2], smaxL[3]));

    int l15 = lane & 15, quad = lane >> 4;
    int f0 = w * 16;
    int shn = (lane & 7) * 4;

    // per-row folded constants (wave w owns rows w*4..w*4+3)
    float c1[4], c2[4], lacc[4];
    #pragma unroll
    for (int rr = 0; rr < 4; ++rr) {
        float sv = s1[(size_t)b * N_ + i0 + w * 4 + rr];   // wave-uniform
        float mm = sv + s2max;
        float mh = fmaxf(mm, ALPHA * mm);    // leaky(s1_i + s2max) >= row max
        c1[rr] = (sv - mh) * LOG2E;
        c2[rr] = (ALPHA * sv - mh) * LOG2E;
        lacc[rr] = 0.f;
    }

    // mask base: row (i0 + w*4), 32-bit word (lane>>3); row stride 64 words
    const unsigned* mB = mask32 + ((size_t)b * N_ + i0 + w * 4) * 64 + (lane >> 3);
    const float* s2L = s2 + (size_t)b * N_ + lane * 4;

    float4v acc = {0.f, 0.f, 0.f, 0.f};
    const _Float16* wB = whT + ((size_t)b * FOUT + f0 + l15) * N_ + quad * 8;

    #pragma unroll 1
    for (int c = 0; c < 8; ++c) {
        // chunk-c loads: 4 mask words (4B broadcast per octet), s2 float4,
        // bf 8xhalf8 -- all L2-resident, all independent
        unsigned mbits[4];
        #pragma unroll
        for (int rr = 0; rr < 4; ++rr)
            mbits[rr] = (mB[(size_t)rr * 64 + c * 8] >> shn) & 0xFu;
        float4 sv = *(const float4*)(s2L + c * 256);
        half8 bfr[8];
        const _Float16* wp = wB + c * 256;
        #pragma unroll
        for (int kk = 0; kk < 8; ++kk) bfr[kk] = *(const half8*)(wp + kk * 32);

        float u[4]  = {sv.x * LOG2E, sv.y * LOG2E, sv.z * LOG2E, sv.w * LOG2E};
        float ua[4] = {u[0] * ALPHA, u[1] * ALPHA, u[2] * ALPHA, u[3] * ALPHA};
        #pragma unroll
        for (int rr = 0; rr < 4; ++rr) {
            int r = w * 4 + rr;
            half4 pf;
            float ls = 0.f;
            #pragma unroll
            for (int e = 0; e < 4; ++e) {
                float tt = fmaxf(c1[rr] + u[e], c2[rr] + ua[e]);
#if __has_builtin(__builtin_amdgcn_exp2f)
                float p = __builtin_amdgcn_exp2f(tt);
#else
                float p = exp2f(tt);
#endif
                p = (mbits[rr] & (1u << e)) ? p : 0.f;   // mask -> exact 0
                ls += p;
                pf[e] = (_Float16)p;
            }
            lacc[rr] += ls;
            *(half4*)&pT[c & 1][r][lane * 4] = pf;
        }

        if (c == 7) {
            // publish row sums before the last barrier
            #pragma unroll
            for (int rr = 0; rr < 4; ++rr) {
                float v = lacc[rr];
                #pragma unroll
                for (int m = 32; m >= 1; m >>= 1) v += __shfl_xor(v, m);
                if (lane == 0) lL[w * 4 + rr] = v;
            }
        }

        __syncthreads();   // publish pT[c&1]; prior-buffer readers proven done

        // MFMA on pT[c&1] with reg-resident B
        #pragma unroll
        for (int kk = 0; kk < 8; ++kk) {
            half8 af = *(const half8*)&pT[c & 1][l15][kk * 32 + quad * 8];
            acc = __builtin_amdgcn_mfma_f32_16x16x32_f16(af, bfr[kk], acc, 0, 0, 0);
        }
    }

    // epilogue: normalize, ELU, store. D: row=quad*4+reg, col=f0+l15
    #pragma unroll
    for (int reg = 0; reg < 4; ++reg) {
        int row = quad * 4 + reg;
        float val = acc[reg] / lL[row];
        val = (val > 0.f) ? val : (__expf(val) - 1.f);   // ELU
        out[((size_t)b * N_ + i0 + row) * FOUT + f0 + l15] = val;
    }
}

// ---------------------------------------------------------------------------
extern "C" void kernel_launch(void* const* d_in, const int* in_sizes, int n_in,
                              void* d_out, int out_size, void* d_ws, size_t ws_size,
                              hipStream_t stream) {
    const float* x   = (const float*)d_in[0];
    const int*   adj = (const int*)d_in[1];
    const float* W   = (const float*)d_in[2];
    const float* w2  = (const float*)d_in[3];
    float* out = (float*)d_out;

    char* ws = (char*)d_ws;
    _Float16* whT = (_Float16*)ws;                              // 2 MiB
    float* s1  = (float*)(ws + 2097152);                        // 64 KiB
    float* s2  = (float*)(ws + 2097152 + 65536);                // 64 KiB
    _Float16* WtG = (_Float16*)(ws + 2097152 + 131072);         // 32 KiB
    unsigned long long* maskp =
        (unsigned long long*)(ws + 2097152 + 131072 + 32768);   // 4 MiB

    k0_convW<<<32, 256, 0, stream>>>(W, WtG);
    kp_pack<<<(B_ * N_) / 4, 256, 0, stream>>>(adj, maskp);
    k1_wh<<<(B_ * N_) / 32, 256, 0, stream>>>(x, WtG, w2, whT, s1, s2);
    k2_attn<<<(B_ * N_) / 16, 256, 0, stream>>>((const unsigned*)maskp, whT, s1, s2, out);
}